// Round 8
// baseline (97.808 us; speedup 1.0000x reference)
//
#include <hip/hip_runtime.h>
#include <hip/hip_bf16.h>

#define BB 8
#define CIN 256
#define COUT 128
#define HIN 128
#define WIN 128
#define HOUT 256
#define WOUT 256

typedef __attribute__((ext_vector_type(8))) short bf16x8;
typedef __attribute__((ext_vector_type(4))) float f32x4;

__device__ __forceinline__ short f2bf(float f) {
  __hip_bfloat16 h = __float2bfloat16(f);  // RNE
  return *reinterpret_cast<short*>(&h);
}
__device__ __forceinline__ float bf2f(short s) {
  unsigned int u = ((unsigned int)(unsigned short)s) << 16;
  return __uint_as_float(u);
}

// ---------------- Kernel 0: W fp32 -> bf16 (row-major [COUT][CIN]) --------
__global__ __launch_bounds__(256) void wconv_kernel(const float* __restrict__ wgt,
                                                    short* __restrict__ wbf) {
  int idx = (blockIdx.x * 256 + threadIdx.x) * 4;
  float4 f = *reinterpret_cast<const float4*>(wgt + idx);
  short4 pk = make_short4(f2bf(f.x), f2bf(f.y), f2bf(f.z), f2bf(f.w));
  *reinterpret_cast<short4*>(wbf + idx) = pk;
}

// ---------------- Kernel 1: z[b][o][h][w] = sum_c W[o][c] x[b][c][h][w] ----
// grid (128, 8), 256 threads. Barrier-free main loop:
//  - XCD-aware h-banding: h = (bx&7)*16 + (bx>>3)  -> each XCD reads a
//    contiguous 16-row band of every c-plane (8KB contiguous per plane).
//  - wave tile 32w x 128o (acc 2x8): A-fragments loaded DIRECTLY from global
//    (8 scalar dwords, cvt in reg), zero cross-wave redundancy, no staging
//    LDS, no syncthreads until epilogue. K-steps software-pipelined (ra/rb).
//  - epilogue: LDS transpose (32KB) -> 256B-contiguous bf16 z stores.
__global__ __launch_bounds__(256, 2) void conv1x1_kernel(const float* __restrict__ x,
                                                         const short* __restrict__ wbf,
                                                         short* __restrict__ zbf) {
  __shared__ __align__(16) short smem[128 * 128];  // 32KB, epilogue only
  const int bx = blockIdx.x, b = blockIdx.y;
  const int h = ((bx & 7) << 4) + (bx >> 3);  // XCD h-banding
  const int t = threadIdx.x;

  const int lane = t & 63, wid = t >> 6;
  const int r = lane & 15, g = lane >> 4;
  const int wbase = wid * 32;

  const float* xq = x + (size_t)b * (CIN * HIN * WIN) + (size_t)h * WIN
                    + (size_t)(g * 8) * (HIN * WIN) + wbase + r;
  const short* wq = wbf + (size_t)r * CIN + g * 8;  // row o=r, chunk g

  f32x4 acc[2][8];
#pragma unroll
  for (int i = 0; i < 2; ++i)
#pragma unroll
    for (int j = 0; j < 8; ++j)
      acc[i][j] = (f32x4){0.f, 0.f, 0.f, 0.f};

  float ra[16], rb[16];

#define LOADK(kk, buf)                                                        \
  {                                                                           \
    _Pragma("unroll") for (int mt = 0; mt < 2; ++mt)                          \
        _Pragma("unroll") for (int i = 0; i < 8; ++i)                         \
            buf[mt * 8 + i] =                                                 \
                xq[(size_t)((kk) * 32 + i) * (HIN * WIN) + mt * 16];          \
  }

#define MFMAK(kk, buf)                                                        \
  {                                                                           \
    bf16x8 xfr[2], wfr[8];                                                    \
    _Pragma("unroll") for (int mt = 0; mt < 2; ++mt) {                        \
      _Pragma("unroll") for (int i = 0; i < 8; ++i)                           \
          xfr[mt][i] = f2bf(buf[mt * 8 + i]);                                 \
    }                                                                         \
    _Pragma("unroll") for (int nt = 0; nt < 8; ++nt)                          \
        wfr[nt] = *reinterpret_cast<const bf16x8*>(wq + (size_t)(nt * 16) * CIN + (kk) * 32); \
    _Pragma("unroll") for (int mt = 0; mt < 2; ++mt)                          \
        _Pragma("unroll") for (int nt = 0; nt < 8; ++nt)                      \
            acc[mt][nt] = __builtin_amdgcn_mfma_f32_16x16x32_bf16(            \
                xfr[mt], wfr[nt], acc[mt][nt], 0, 0, 0);                      \
  }

  LOADK(0, ra)
#pragma unroll
  for (int ks2 = 0; ks2 < 4; ++ks2) {
    const int k0 = ks2 * 2;
    LOADK(k0 + 1, rb)
    MFMAK(k0, ra)
    if (k0 + 2 < 8) LOADK(k0 + 2, ra)
    MFMAK(k0 + 1, rb)
  }
#undef LOADK
#undef MFMAK

  __syncthreads();  // epilogue smem use (no prior LDS writes, pure entry sync)

  // acc -> zs[o][w] bf16 in LDS (16B-chunk XOR swizzle), then coalesced
  // 256B-contiguous stores per o-row.
#pragma unroll
  for (int mt = 0; mt < 2; ++mt) {
#pragma unroll
    for (int nt = 0; nt < 8; ++nt) {
      int o = nt * 16 + r;
      int w4 = wbase + mt * 16 + g * 4;
      int cw = w4 >> 3, sub = w4 & 7;
      short4 pk = make_short4(f2bf(acc[mt][nt][0]), f2bf(acc[mt][nt][1]),
                              f2bf(acc[mt][nt][2]), f2bf(acc[mt][nt][3]));
      *reinterpret_cast<short4*>(&smem[o * 128 + ((cw ^ (o & 15)) << 3) + sub]) = pk;
    }
  }
  __syncthreads();

  short* zb = zbf + (size_t)b * (COUT * HIN * WIN) + (size_t)h * WIN;
  const int ck = t & 15;
#pragma unroll
  for (int p = 0; p < 8; ++p) {
    int ro = p * 16 + (t >> 4);
    bf16x8 v = *reinterpret_cast<const bf16x8*>(&smem[ro * 128 + ((ck ^ (ro & 15)) << 3)]);
    *reinterpret_cast<bf16x8*>(zb + (size_t)ro * (HIN * WIN) + ck * 8) = v;
  }
}

// ---------------- Kernel 2: separable bicubic 2x + bias + LeakyReLU -------
#define ACF (-0.75f)
#define NEG 0.01f

__device__ __forceinline__ float cub_le1(float s) {
  return ((ACF + 2.0f) * s - (ACF + 3.0f)) * s * s + 1.0f;
}
__device__ __forceinline__ float cub_gt1(float s) {
  return (((s - 5.0f) * s + 8.0f) * s - 4.0f) * ACF;
}
__device__ __forceinline__ float4 mkw(float tt) {
  return make_float4(cub_gt1(1.0f + tt), cub_le1(tt), cub_le1(1.0f - tt), cub_gt1(2.0f - tt));
}

__global__ __launch_bounds__(256) void upsample_kernel(const short* __restrict__ zbf,
                                                       const float* __restrict__ bias,
                                                       float* __restrict__ out) {
  __shared__ float zrow[20][128];
  __shared__ float trow[20][256];

  const int bx = blockIdx.x;
  const int itile = bx & 7;
  const int o = bx >> 3;
  const int b = blockIdx.y;
  const int t = threadIdx.x;

  const int m0 = itile * 16;
  const int hmin = max(m0 - 2, 0);
  const int hmax = min(m0 + 15 + 2, HIN - 1);
  const int nh = hmax - hmin + 1;  // <= 20

  {
    const short* zb = zbf + ((size_t)b * COUT + o) * (HIN * WIN);
    for (int q = t; q < nh * 16; q += 256) {
      int hr = q >> 4, c8 = (q & 15) * 8;
      bf16x8 v = *reinterpret_cast<const bf16x8*>(zb + (size_t)(hmin + hr) * WIN + c8);
      float4 lo = make_float4(bf2f(v[0]), bf2f(v[1]), bf2f(v[2]), bf2f(v[3]));
      float4 hi = make_float4(bf2f(v[4]), bf2f(v[5]), bf2f(v[6]), bf2f(v[7]));
      *reinterpret_cast<float4*>(&zrow[hr][c8]) = lo;
      *reinterpret_cast<float4*>(&zrow[hr][c8 + 4]) = hi;
    }
  }
  __syncthreads();

  {
    const int u = t & 127;
    const int pr = t >> 7;
    const float uf = (float)u;
    const float4 wA = mkw((255.0f - uf) * (1.0f / 255.0f));
    const float4 wB = mkw((127.0f - uf) * (1.0f / 255.0f));
    const int i0c = max(u - 2, 0);
    const int i1c = max(u - 1, 0);
    const int i2c = u;
    const int i3c = min(u + 1, WIN - 1);
    const int i4c = min(u + 2, WIN - 1);
    for (int hr = pr; hr < nh; hr += 2) {
      float z0 = zrow[hr][i0c], z1 = zrow[hr][i1c], z2 = zrow[hr][i2c];
      float z3 = zrow[hr][i3c], z4 = zrow[hr][i4c];
      float oa = wA.x * z0 + wA.y * z1 + wA.z * z2 + wA.w * z3;
      float ob = wB.x * z1 + wB.y * z2 + wB.z * z3 + wB.w * z4;
      *reinterpret_cast<float2*>(&trow[hr][u * 2]) = make_float2(oa, ob);
    }
  }
  __syncthreads();

  const float bv = bias[o];
  const int j4 = t & 63;
  const int iw = t >> 6;
  float* obase = out + ((size_t)b * COUT + o) * (HOUT * WOUT);
  for (int mm = iw; mm < 16; mm += 4) {
    int m = m0 + mm;
    float mf = (float)m;
    float4 wA = mkw((255.0f - mf) * (1.0f / 255.0f));
    float4 wB = mkw((127.0f - mf) * (1.0f / 255.0f));
    int r0 = max(m - 2, 0) - hmin;
    int r1 = max(m - 1, 0) - hmin;
    int r2 = m - hmin;
    int r3 = min(m + 1, HIN - 1) - hmin;
    int r4 = min(m + 2, HIN - 1) - hmin;
    float4 t0 = *reinterpret_cast<const float4*>(&trow[r0][j4 * 4]);
    float4 t1 = *reinterpret_cast<const float4*>(&trow[r1][j4 * 4]);
    float4 t2 = *reinterpret_cast<const float4*>(&trow[r2][j4 * 4]);
    float4 t3 = *reinterpret_cast<const float4*>(&trow[r3][j4 * 4]);
    float4 t4 = *reinterpret_cast<const float4*>(&trow[r4][j4 * 4]);
    f32x4 rA, rB;
    rA.x = wA.x * t0.x + wA.y * t1.x + wA.z * t2.x + wA.w * t3.x + bv;
    rA.y = wA.x * t0.y + wA.y * t1.y + wA.z * t2.y + wA.w * t3.y + bv;
    rA.z = wA.x * t0.z + wA.y * t1.z + wA.z * t2.z + wA.w * t3.z + bv;
    rA.w = wA.x * t0.w + wA.y * t1.w + wA.z * t2.w + wA.w * t3.w + bv;
    rB.x = wB.x * t1.x + wB.y * t2.x + wB.z * t3.x + wB.w * t4.x + bv;
    rB.y = wB.x * t1.y + wB.y * t2.y + wB.z * t3.y + wB.w * t4.y + bv;
    rB.z = wB.x * t1.z + wB.y * t2.z + wB.z * t3.z + wB.w * t4.z + bv;
    rB.w = wB.x * t1.w + wB.y * t2.w + wB.z * t3.w + wB.w * t4.w + bv;
    rA.x = rA.x >= 0.f ? rA.x : rA.x * NEG;
    rA.y = rA.y >= 0.f ? rA.y : rA.y * NEG;
    rA.z = rA.z >= 0.f ? rA.z : rA.z * NEG;
    rA.w = rA.w >= 0.f ? rA.w : rA.w * NEG;
    rB.x = rB.x >= 0.f ? rB.x : rB.x * NEG;
    rB.y = rB.y >= 0.f ? rB.y : rB.y * NEG;
    rB.z = rB.z >= 0.f ? rB.z : rB.z * NEG;
    rB.w = rB.w >= 0.f ? rB.w : rB.w * NEG;
    int iA = itile * 32 + 2 * mm;
    __builtin_nontemporal_store(rA, reinterpret_cast<f32x4*>(obase + (size_t)iA * WOUT + j4 * 4));
    __builtin_nontemporal_store(rB, reinterpret_cast<f32x4*>(obase + (size_t)(iA + 1) * WOUT + j4 * 4));
  }
}

extern "C" void kernel_launch(void* const* d_in, const int* in_sizes, int n_in,
                              void* d_out, int out_size, void* d_ws, size_t ws_size,
                              hipStream_t stream) {
  const float* x = (const float*)d_in[0];
  const float* wgt = (const float*)d_in[1];
  const float* bias = (const float*)d_in[2];
  float* out = (float*)d_out;

  short* zbf = (short*)d_ws;
  short* wbf = (short*)((char*)d_ws + (size_t)BB * COUT * HIN * WIN * sizeof(short));

  wconv_kernel<<<dim3(COUT * CIN / (256 * 4)), 256, 0, stream>>>(wgt, wbf);
  conv1x1_kernel<<<dim3(HIN, BB), 256, 0, stream>>>(x, wbf, zbf);
  upsample_kernel<<<dim3(COUT * 8, BB), 256, 0, stream>>>(zbf, bias, out);
}